// Round 4
// baseline (1219.398 us; speedup 1.0000x reference)
//
#include <hip/hip_runtime.h>
#include <hip/hip_bf16.h>

// B=16384, IN_DIM=4096, T=6, H=256.
// bf16x3 split-precision MFMA GEMMs (acc += ah*bh + ah*bl + al*bh).
// R4: T3-minimum 2-phase double-buffered K-loop -- prefetch tile t+1 into the
// idle LDS buffer BEFORE the MFMA block, one __syncthreads per K-step, so the
// global_load_lds / global-load latency and the fp32->bf16x2 split VALU work
// overlap with MFMA instead of being barrier-serialized (R1/R3 measured the
// 1-phase structure at its known ~900 TF ceiling, 20% barrier drain).
// Reverted to __launch_bounds__(256,2) (R3's (256,4) regressed 10% uniformly).
// Kept XCD-bijective block swizzle (FETCH 1.27->0.74 GB, verified).
// NOTE: chunk swizzles proven unable to move SQ_LDS_BANK_CONFLICT (identical
// 7.55e7 under two variants; 64B row stride aliases banks mod 2) -- left as-is.
//
// ws layout (bytes):
//   [0,6144)            qk            f32 [6][256]
//   [6144,7168)         vbar          f32 [256]
//   [7168,7200)         qb            f32 [6]
//   [7200,7204)         vbbar         f32
//   [8192, +50331648)   h1h           bf16 [16384][1536]
//   [50339840, +50331648) h1l         bf16
//   [100671488, +100663296) h2        f32  [16384][6][256]
//   [201334784, +2359296)  L          f32  [16384][6][6]
//   [203694080, +393216)   Vm         f32  [16384][6]
//   [204087296, +12582912) w1h        bf16 [1536][4096]
//   [216670208, +12582912) w1l
//   [229253120, +786432)   w2h        bf16 [6][256][256]
//   [230039552, +786432)   w2l        (end 230825984 ~ 231 MB)

typedef float    f32x4 __attribute__((ext_vector_type(4)));
typedef short    s16x8 __attribute__((ext_vector_type(8)));
typedef unsigned short u16x4 __attribute__((ext_vector_type(4)));

__global__ void M3H_64587718197825_kernel() {}

__device__ __forceinline__ unsigned short bf16rn(float x) {
    unsigned u = __float_as_uint(x);
    return (unsigned short)((u + 0x7FFFu + ((u >> 16) & 1u)) >> 16);
}
__device__ __forceinline__ float bf16tof(unsigned short h) {
    return __uint_as_float(((unsigned)h) << 16);
}

// ---- staging helpers -------------------------------------------------------
// LDS tile layout: [128 rows][4 chunks of 8 bf16]; slot (r, c) holds global
// k-chunk (c ^ s(r)) with s(r) = (r + (r>>2)) & 3 (involution on both sides).

__device__ __forceinline__ void stage_lds16(const unsigned short* src, int ld,
                                            unsigned short* lds, int tid)
{
#pragma unroll
    for (int t = 0; t < 2; ++t) {
        int c  = t * 256 + tid;          // chunk 0..511
        int r  = c >> 2;                 // row 0..127
        int cr = c & 3;                  // slot-in-row
        int s  = (r + (r >> 2)) & 3;
        long long g = (long long)r * ld + ((cr ^ s) << 3);
        __builtin_amdgcn_global_load_lds(
            (const __attribute__((address_space(1))) unsigned int*)(const void*)(src + g),
            (__attribute__((address_space(3))) unsigned int*)(void*)(lds + (c << 3)),
            16, 0, 0);
    }
}

// fp32 A tile [128][32]: load phase (global->regs) and write phase (split ->
// swizzled ds_write), separated so the split+write can sit after the MFMAs.
struct AReg { float4 v0, v1, v2, v3; };

__device__ __forceinline__ AReg stage_a_load(const float* Atile, int lda, int tid)
{
    int r = tid >> 1;
    int h = tid & 1;
    const float* ap = Atile + (long long)r * lda + (h << 4);
    AReg a;
    a.v0 = *(const float4*)(ap + 0);
    a.v1 = *(const float4*)(ap + 4);
    a.v2 = *(const float4*)(ap + 8);
    a.v3 = *(const float4*)(ap + 12);
    return a;
}

__device__ __forceinline__ void stage_a_write(const AReg& a,
                                              unsigned short* sAh, unsigned short* sAl,
                                              int tid)
{
    int r = tid >> 1;
    int h = tid & 1;
    float xs[16];
    xs[0]=a.v0.x; xs[1]=a.v0.y; xs[2]=a.v0.z;  xs[3]=a.v0.w;
    xs[4]=a.v1.x; xs[5]=a.v1.y; xs[6]=a.v1.z;  xs[7]=a.v1.w;
    xs[8]=a.v2.x; xs[9]=a.v2.y; xs[10]=a.v2.z; xs[11]=a.v2.w;
    xs[12]=a.v3.x; xs[13]=a.v3.y; xs[14]=a.v3.z; xs[15]=a.v3.w;
    s16x8 hv0, hv1, lv0, lv1;
#pragma unroll
    for (int i = 0; i < 8; ++i) {
        unsigned short hb = bf16rn(xs[i]);
        hv0[i] = (short)hb;
        lv0[i] = (short)bf16rn(xs[i] - bf16tof(hb));
    }
#pragma unroll
    for (int i = 0; i < 8; ++i) {
        unsigned short hb = bf16rn(xs[8 + i]);
        hv1[i] = (short)hb;
        lv1[i] = (short)bf16rn(xs[8 + i] - bf16tof(hb));
    }
    int s  = (r + (r >> 2)) & 3;
    int c0 = ((h << 1) | 0) ^ s;
    int c1 = ((h << 1) | 1) ^ s;
    int base = r << 5;
    *(s16x8*)(sAh + base + (c0 << 3)) = hv0;
    *(s16x8*)(sAh + base + (c1 << 3)) = hv1;
    *(s16x8*)(sAl + base + (c0 << 3)) = lv0;
    *(s16x8*)(sAl + base + (c1 << 3)) = lv1;
}

// ---- MFMA GEMM -------------------------------------------------------------
// C[M,N] = relu(A[M,K] * B[N,K]^T + bias[N]).
// 128x128 tile, BK=32, 256 threads (4 waves, 2x2 of 64x64 wave-tiles),
// double-buffered LDS, 1 barrier / K-step, 48 MFMA / K-step / wave.
template<bool SPLIT_A, bool WRITE_SPLIT>
__global__ __launch_bounds__(256, 2) void gemm_bf16x3(
    const float* A32, const unsigned short* Ah, const unsigned short* Al,
    const unsigned short* Bh, const unsigned short* Bl,
    const float* bias, float* C32, unsigned short* Ch, unsigned short* Cl,
    int K, int lda, int ldb, int ldc,
    long long aOffZ, long long bOffZ, long long cOffZ, long long biasOffZ)
{
    int z = blockIdx.z;
    if constexpr (SPLIT_A) {
        A32 += (long long)z * aOffZ;
    } else {
        Ah += (long long)z * aOffZ;
        Al += (long long)z * aOffZ;
    }
    Bh += (long long)z * bOffZ;
    Bl += (long long)z * bOffZ;
    bias += (long long)z * biasOffZ;
    if constexpr (WRITE_SPLIT) {
        Ch += (long long)z * cOffZ;
        Cl += (long long)z * cOffZ;
    } else {
        C32 += (long long)z * cOffZ;
    }

    __shared__ __attribute__((aligned(16))) unsigned short sAh[2][4096];
    __shared__ __attribute__((aligned(16))) unsigned short sAl[2][4096];
    __shared__ __attribute__((aligned(16))) unsigned short sBh[2][4096];
    __shared__ __attribute__((aligned(16))) unsigned short sBl[2][4096];

    // XCD-bijective block swizzle (m204): blocks sharing an A-panel land on
    // the same XCD's L2 (FETCH 1.27 -> 0.74 GB measured).
    int nwg = gridDim.x * gridDim.y;
    int lin = blockIdx.y * gridDim.x + blockIdx.x;
    int qq = nwg >> 3, rr = nwg & 7;
    int xcd = lin & 7, idx = lin >> 3;
    int swz = (xcd < rr ? xcd * (qq + 1) : rr * (qq + 1) + (xcd - rr) * qq) + idx;
    const int tm = (swz / gridDim.x) * 128;
    const int tn = (swz % gridDim.x) * 128;

    const int tid  = threadIdx.x;
    const int lane = tid & 63;
    const int wid  = tid >> 6;
    const int wm = (wid & 1) << 6;       // wave row offset (0/64)
    const int wn = (wid >> 1) << 6;      // wave col offset (0/64)
    const int fr = lane & 15;            // fragment row/col index
    const int fk = lane >> 4;            // k-chunk 0..3
    const int swz8 = ((fk ^ ((fr + (fr >> 2)) & 3)) << 3);

    const float* aBase = SPLIT_A ? (A32 + (long long)tm * lda) : nullptr;
    const unsigned short* ahBase = SPLIT_A ? nullptr : (Ah + (long long)tm * lda);
    const unsigned short* alBase = SPLIT_A ? nullptr : (Al + (long long)tm * lda);
    const unsigned short* bhBase = Bh + (long long)tn * ldb;
    const unsigned short* blBase = Bl + (long long)tn * ldb;

    f32x4 acc[4][4];
    const f32x4 zero = {0.f, 0.f, 0.f, 0.f};
#pragma unroll
    for (int i = 0; i < 4; ++i)
#pragma unroll
        for (int j = 0; j < 4; ++j)
            acc[i][j] = zero;

    // prologue: stage tile 0 into buffer 0
    if constexpr (SPLIT_A) {
        AReg a0 = stage_a_load(aBase, lda, tid);
        stage_a_write(a0, sAh[0], sAl[0], tid);
    } else {
        stage_lds16(ahBase, lda, sAh[0], tid);
        stage_lds16(alBase, lda, sAl[0], tid);
    }
    stage_lds16(bhBase, ldb, sBh[0], tid);
    stage_lds16(blBase, ldb, sBl[0], tid);
    __syncthreads();

    const int nt = K >> 5;
    for (int t = 0; t < nt; ++t) {
        const int P = t & 1, Q = P ^ 1;
        const bool pf = (t + 1 < nt);
        const int k1 = (t + 1) << 5;

        // prefetch t+1 into idle buffer Q (issued before MFMA block)
        AReg nxt;
        if (pf) {
            if constexpr (SPLIT_A) {
                nxt = stage_a_load(aBase + k1, lda, tid);
            } else {
                stage_lds16(ahBase + k1, lda, sAh[Q], tid);
                stage_lds16(alBase + k1, lda, sAl[Q], tid);
            }
            stage_lds16(bhBase + k1, ldb, sBh[Q], tid);
            stage_lds16(blBase + k1, ldb, sBl[Q], tid);
        }

        // compute from buffer P
        s16x8 bh[4], bl[4];
#pragma unroll
        for (int ni = 0; ni < 4; ++ni) {
            int off = (wn + ni * 16 + fr) * 32 + swz8;
            bh[ni] = *(const s16x8*)(sBh[P] + off);
            bl[ni] = *(const s16x8*)(sBl[P] + off);
        }
#pragma unroll
        for (int mi = 0; mi < 4; ++mi) {
            int off = (wm + mi * 16 + fr) * 32 + swz8;
            s16x8 ah = *(const s16x8*)(sAh[P] + off);
            s16x8 al = *(const s16x8*)(sAl[P] + off);
#pragma unroll
            for (int ni = 0; ni < 4; ++ni) {
                acc[mi][ni] = __builtin_amdgcn_mfma_f32_16x16x32_bf16(ah, bh[ni], acc[mi][ni], 0, 0, 0);
                acc[mi][ni] = __builtin_amdgcn_mfma_f32_16x16x32_bf16(ah, bl[ni], acc[mi][ni], 0, 0, 0);
                acc[mi][ni] = __builtin_amdgcn_mfma_f32_16x16x32_bf16(al, bh[ni], acc[mi][ni], 0, 0, 0);
            }
        }

        // write-late: split next A tile into LDS after the MFMAs
        if constexpr (SPLIT_A) {
            if (pf) stage_a_write(nxt, sAh[Q], sAl[Q], tid);
        }
        __syncthreads();
    }

    // epilogue: D row = (lane>>4)*4 + reg, col = lane&15 (verified C/D layout)
#pragma unroll
    for (int mi = 0; mi < 4; ++mi) {
        int crow = tm + wm + mi * 16 + fk * 4;
#pragma unroll
        for (int ni = 0; ni < 4; ++ni) {
            int ccol = tn + wn + ni * 16 + fr;
            float bv = bias[ccol];
#pragma unroll
            for (int rr2 = 0; rr2 < 4; ++rr2) {
                float v = acc[mi][ni][rr2] + bv;
                v = v > 0.f ? v : 0.f;
                long long ci = (long long)(crow + rr2) * ldc + ccol;
                if constexpr (WRITE_SPLIT) {
                    unsigned short hb = bf16rn(v);
                    Ch[ci] = hb;
                    Cl[ci] = bf16rn(v - bf16tof(hb));
                } else {
                    C32[ci] = v;
                }
            }
        }
    }
}

// split an fp32 array into bf16 hi/lo arrays; n4 = count/4
__global__ void split_ws(const float* in, unsigned short* hi, unsigned short* lo, int n4)
{
    for (int i = blockIdx.x * 256 + threadIdx.x; i < n4; i += gridDim.x * 256) {
        float4 v = ((const float4*)in)[i];
        float xs[4] = {v.x, v.y, v.z, v.w};
        u16x4 hv, lv;
#pragma unroll
        for (int j = 0; j < 4; ++j) {
            unsigned short hb = bf16rn(xs[j]);
            hv[j] = hb;
            lv[j] = bf16rn(xs[j] - bf16tof(hb));
        }
        ((u16x4*)hi)[i] = hv;
        ((u16x4*)lo)[i] = lv;
    }
}

// one block, 256 threads; thread h computes qk[q][h], vbar[h]
__global__ void precompute(const float* tq, const float* keyW, const float* keyb,
                           const float* valW, const float* valb,
                           float* qk, float* qb, float* vbar, float* vbbar)
{
    __shared__ float tqs[1536];
    int h = threadIdx.x;
    for (int i = h; i < 1536; i += 256) tqs[i] = tq[i];
    __syncthreads();
    float acc0 = 0.f, acc1 = 0.f, acc2 = 0.f, acc3 = 0.f, acc4 = 0.f, acc5 = 0.f;
    float vb = 0.f;
    for (int o = 0; o < 256; ++o) {
        float kw = keyW[o * 256 + h];
        float vw = valW[o * 256 + h];
        acc0 += tqs[0 * 256 + o] * kw;
        acc1 += tqs[1 * 256 + o] * kw;
        acc2 += tqs[2 * 256 + o] * kw;
        acc3 += tqs[3 * 256 + o] * kw;
        acc4 += tqs[4 * 256 + o] * kw;
        acc5 += tqs[5 * 256 + o] * kw;
        vb += vw;
    }
    qk[0 * 256 + h] = acc0;
    qk[1 * 256 + h] = acc1;
    qk[2 * 256 + h] = acc2;
    qk[3 * 256 + h] = acc3;
    qk[4 * 256 + h] = acc4;
    qk[5 * 256 + h] = acc5;
    vbar[h] = vb * (1.0f / 256.0f);
    if (h < 6) {
        float s = 0.f;
        for (int o = 0; o < 256; ++o) s += tq[h * 256 + o] * keyb[o];
        qb[h] = s;
    }
    if (h == 6) {
        float s = 0.f;
        for (int o = 0; o < 256; ++o) s += valb[o];
        vbbar[0] = s * (1.0f / 256.0f);
    }
}

// thread per row (b,k) of h2[B*6][256]: 7 dots with U = {qk[0..5], vbar}
__global__ void dots(const float* h2, const float* qk, const float* qb,
                     const float* vbar, const float* vbbar,
                     float* L, float* Vm)
{
    __shared__ float U[7][256];
    __shared__ float qbs[8];
    int tid = threadIdx.x;
    for (int i = tid; i < 1792; i += 256)
        U[i >> 8][i & 255] = (i < 1536) ? qk[i] : vbar[i & 255];
    if (tid < 6) qbs[tid] = qb[tid];
    if (tid == 6) qbs[6] = vbbar[0];
    __syncthreads();
    int row = blockIdx.x * 256 + tid;          // 98304 rows, 384 blocks exact
    const float* hr = h2 + (long long)row * 256;
    float a0 = 0.f, a1 = 0.f, a2 = 0.f, a3 = 0.f, a4 = 0.f, a5 = 0.f, a6 = 0.f;
    for (int i = 0; i < 256; i += 4) {
        float4 v = *(const float4*)(hr + i);
        float xs[4];
        xs[0] = v.x; xs[1] = v.y; xs[2] = v.z; xs[3] = v.w;
        for (int j = 0; j < 4; ++j) {
            float x = xs[j];
            int c = i + j;
            a0 += x * U[0][c];
            a1 += x * U[1][c];
            a2 += x * U[2][c];
            a3 += x * U[3][c];
            a4 += x * U[4][c];
            a5 += x * U[5][c];
            a6 += x * U[6][c];
        }
    }
    int b = row / 6, k = row - b * 6;
    float* Lr = L + (long long)b * 36 + k;
    Lr[0 * 6]  = (a0 + qbs[0]) * 0.0625f;
    Lr[1 * 6]  = (a1 + qbs[1]) * 0.0625f;
    Lr[2 * 6]  = (a2 + qbs[2]) * 0.0625f;
    Lr[3 * 6]  = (a3 + qbs[3]) * 0.0625f;
    Lr[4 * 6]  = (a4 + qbs[4]) * 0.0625f;
    Lr[5 * 6]  = (a5 + qbs[5]) * 0.0625f;
    Vm[row] = a6 + qbs[6];
}

// thread per b: 6x6 softmax + sigmoid + clip
__global__ void attn(const float* L, const float* Vm, const float* biasp, float* out)
{
    int b = blockIdx.x * 256 + threadIdx.x;    // 16384, 64 blocks exact
    float bias = biasp[0];
    float l[36], vm[6];
    const float* Lr = L + (long long)b * 36;
    for (int i = 0; i < 36; ++i) l[i] = Lr[i];
    for (int k = 0; k < 6; ++k) vm[k] = Vm[(long long)b * 6 + k];
    for (int q = 0; q < 6; ++q) {
        float m = l[q * 6];
        for (int k = 1; k < 6; ++k) m = fmaxf(m, l[q * 6 + k]);
        m += 1e-8f;
        float arg[6];
        float mx = -3.402823e38f;
        for (int k = 0; k < 6; ++k) {
            arg[k] = (k == q ? 1.0f : 0.0f) + 0.1f * l[q * 6 + k] / m;
            mx = fmaxf(mx, arg[k]);
        }
        float s = 0.f, y = 0.f;
        for (int k = 0; k < 6; ++k) {
            float e = expf(arg[k] - mx);
            s += e;
            y += e * vm[k];
        }
        y /= s;
        float p = 1.0f / (1.0f + expf(-(y - bias)));
        p = fminf(fmaxf(p, 1e-7f), 1.0f - 1e-7f);
        out[(long long)b * 6 + q] = p;
    }
}

extern "C" void kernel_launch(void* const* d_in, const int* in_sizes, int n_in,
                              void* d_out, int out_size, void* d_ws, size_t ws_size,
                              hipStream_t stream)
{
    const float* x      = (const float*)d_in[0];
    const float* headW1 = (const float*)d_in[1];
    const float* headb1 = (const float*)d_in[2];
    const float* headW2 = (const float*)d_in[3];
    const float* headb2 = (const float*)d_in[4];
    const float* tq     = (const float*)d_in[5];
    const float* keyW   = (const float*)d_in[6];
    const float* keyb   = (const float*)d_in[7];
    const float* valW   = (const float*)d_in[8];
    const float* valb   = (const float*)d_in[9];
    const float* biasp  = (const float*)d_in[10];
    float* out = (float*)d_out;

    char* w = (char*)d_ws;
    float* qk    = (float*)(w + 0);
    float* vbar  = (float*)(w + 6144);
    float* qb    = (float*)(w + 7168);
    float* vbbar = (float*)(w + 7200);
    unsigned short* h1h = (unsigned short*)(w + 8192);
    unsigned short* h1l = (unsigned short*)(w + 50339840LL);
    float* h2 = (float*)(w + 100671488LL);
    float* L  = (float*)(w + 201334784LL);
    float* Vm = (float*)(w + 203694080LL);
    unsigned short* w1h = (unsigned short*)(w + 204087296LL);
    unsigned short* w1l = (unsigned short*)(w + 216670208LL);
    unsigned short* w2h = (unsigned short*)(w + 229253120LL);
    unsigned short* w2l = (unsigned short*)(w + 230039552LL);

    // split weights into bf16 hi/lo
    split_ws<<<1024, 256, 0, stream>>>(headW1, w1h, w1l, 1572864);
    split_ws<<<384,  256, 0, stream>>>(headW2, w2h, w2l, 98304);

    precompute<<<1, 256, 0, stream>>>(tq, keyW, keyb, valW, valb, qk, qb, vbar, vbbar);

    // stage1: M=16384 N=1536 K=4096; A=x fp32 (fused split), B=w1 pre-split,
    // C -> h1 bf16 hi/lo [16384][1536]
    gemm_bf16x3<true, true><<<dim3(12, 128, 1), 256, 0, stream>>>(
        x, nullptr, nullptr, w1h, w1l, headb1, nullptr, h1h, h1l,
        4096, 4096, 4096, 1536, 0, 0, 0, 0);

    // stage2 (per task z): M=16384 N=256 K=256; A=h1 pre-split (lda=1536,
    // +z*256), B=w2[z], C=h2 fp32 (ldc=1536, +z*256), bias=headb2[z]
    gemm_bf16x3<false, false><<<dim3(2, 128, 6), 256, 0, stream>>>(
        nullptr, h1h, h1l, w2h, w2l, headb2, h2, nullptr, nullptr,
        256, 1536, 256, 1536, 256, 65536, 256, 256);

    dots<<<384, 256, 0, stream>>>(h2, qk, qb, vbar, vbbar, L, Vm);
    attn<<<64, 256, 0, stream>>>(L, Vm, biasp, out);
}

// Round 6
// 1024.473 us; speedup vs baseline: 1.1903x; 1.1903x over previous
//
#include <hip/hip_runtime.h>
#include <hip/hip_bf16.h>

// B=16384, IN_DIM=4096, T=6, H=256.
// bf16x3 split-precision MFMA GEMMs (acc += ah*bh + ah*bl + al*bh).
// R6 (= R5 + bias-gate fix): (1) GEMM core = R1-exact single-buffer structure
// (measured at the 2-phase structural ceiling, 903 TF). (2) dots FUSED into
// stage2 epilogue: h2 never materialized (saves 100MB write + 100MB read +
// a dispatch). Partial dots per block, 16-lane shfl reduce, atomicAdd.
// FIX vs R5: constant (qb/vbbar) injected only by the (tn==0 && wn==0) wave
// -- R5 would have double-added it (2 waves per row at tn==0).
// (3) precompute parallelized to 7 blocks. (4) zeroLV inits L/Vm.
// Kept XCD-bijective block swizzle (FETCH 1.27->0.74 GB verified).
//
// ws layout (bytes):
//   [0,6144)            qk            f32 [6][256]
//   [6144,7168)         vbar          f32 [256]
//   [7168,7200)         qb            f32 [6]
//   [7200,7204)         vbbar         f32
//   [8192, +50331648)   h1h           bf16 [16384][1536]
//   [50339840, +50331648) h1l         bf16
//   [201334784, +2359296)  L          f32  [16384][6][6]
//   [203694080, +393216)   Vm         f32  [16384][6]
//   [204087296, +12582912) w1h        bf16 [1536][4096]
//   [216670208, +12582912) w1l
//   [229253120, +786432)   w2h        bf16 [6][256][256]
//   [230039552, +786432)   w2l        (end 230825984 ~ 231 MB)

typedef float    f32x4 __attribute__((ext_vector_type(4)));
typedef short    s16x8 __attribute__((ext_vector_type(8)));
typedef unsigned short u16x4 __attribute__((ext_vector_type(4)));

__global__ void M3H_64587718197825_kernel() {}

__device__ __forceinline__ unsigned short bf16rn(float x) {
    unsigned u = __float_as_uint(x);
    return (unsigned short)((u + 0x7FFFu + ((u >> 16) & 1u)) >> 16);
}
__device__ __forceinline__ float bf16tof(unsigned short h) {
    return __uint_as_float(((unsigned)h) << 16);
}

// ---- staging helpers -------------------------------------------------------
// LDS tile layout: [128 rows][4 chunks of 8 bf16]; slot (r, c) holds global
// k-chunk (c ^ s(r)) with s(r) = (r + (r>>2)) & 3 (involution on both sides).

__device__ __forceinline__ void stage_lds16(const unsigned short* src, int ld,
                                            unsigned short* lds, int tid)
{
#pragma unroll
    for (int t = 0; t < 2; ++t) {
        int c  = t * 256 + tid;          // chunk 0..511
        int r  = c >> 2;                 // row 0..127
        int cr = c & 3;                  // slot-in-row
        int s  = (r + (r >> 2)) & 3;
        long long g = (long long)r * ld + ((cr ^ s) << 3);
        __builtin_amdgcn_global_load_lds(
            (const __attribute__((address_space(1))) unsigned int*)(const void*)(src + g),
            (__attribute__((address_space(3))) unsigned int*)(void*)(lds + (c << 3)),
            16, 0, 0);
    }
}

// fp32 A tile [128][32]: load, split to bf16 hi/lo, ds_write into the same
// swizzled layout.  thread -> row tid>>1, k-half tid&1.
__device__ __forceinline__ void stage_split_a(const float* Atile, int lda,
                                              unsigned short* sAh, unsigned short* sAl,
                                              int tid)
{
    int r = tid >> 1;
    int h = tid & 1;
    const float* ap = Atile + (long long)r * lda + (h << 4);
    float4 v0 = *(const float4*)(ap + 0);
    float4 v1 = *(const float4*)(ap + 4);
    float4 v2 = *(const float4*)(ap + 8);
    float4 v3 = *(const float4*)(ap + 12);
    float xs[16];
    xs[0]=v0.x; xs[1]=v0.y; xs[2]=v0.z;  xs[3]=v0.w;
    xs[4]=v1.x; xs[5]=v1.y; xs[6]=v1.z;  xs[7]=v1.w;
    xs[8]=v2.x; xs[9]=v2.y; xs[10]=v2.z; xs[11]=v2.w;
    xs[12]=v3.x; xs[13]=v3.y; xs[14]=v3.z; xs[15]=v3.w;
    s16x8 hv0, hv1, lv0, lv1;
#pragma unroll
    for (int i = 0; i < 8; ++i) {
        unsigned short hb = bf16rn(xs[i]);
        hv0[i] = (short)hb;
        lv0[i] = (short)bf16rn(xs[i] - bf16tof(hb));
    }
#pragma unroll
    for (int i = 0; i < 8; ++i) {
        unsigned short hb = bf16rn(xs[8 + i]);
        hv1[i] = (short)hb;
        lv1[i] = (short)bf16rn(xs[8 + i] - bf16tof(hb));
    }
    int s  = (r + (r >> 2)) & 3;
    int c0 = ((h << 1) | 0) ^ s;
    int c1 = ((h << 1) | 1) ^ s;
    int base = r << 5;
    *(s16x8*)(sAh + base + (c0 << 3)) = hv0;
    *(s16x8*)(sAh + base + (c1 << 3)) = hv1;
    *(s16x8*)(sAl + base + (c0 << 3)) = lv0;
    *(s16x8*)(sAl + base + (c1 << 3)) = lv1;
}

// ---- MFMA GEMM -------------------------------------------------------------
// C[M,N] = relu(A[M,K] * B[N,K]^T + bias[N]).
// SPLIT_A: A fp32, split fused into staging.  WRITE_SPLIT: C -> bf16 hi/lo.
// FUSE: no C write; instead compute partial dots with U={qk[0..5],vbar} and
// atomicAdd into L/Vm (stage2+dots fusion).
// 128x128 tile, BK=32, 256 threads (4 waves, 2x2 of 64x64 wave-tiles),
// single-buffer LDS, 2 barriers / K-step (R1-verified structure).
template<bool SPLIT_A, bool WRITE_SPLIT, bool FUSE>
__global__ __launch_bounds__(256, 2) void gemm_bf16x3(
    const float* A32, const unsigned short* Ah, const unsigned short* Al,
    const unsigned short* Bh, const unsigned short* Bl,
    const float* bias, float* C32, unsigned short* Ch, unsigned short* Cl,
    const float* qk, const float* qb, const float* vbar, const float* vbbar,
    float* L, float* Vm,
    int K, int lda, int ldb, int ldc,
    long long aOffZ, long long bOffZ, long long cOffZ, long long biasOffZ)
{
    int z = blockIdx.z;
    if constexpr (SPLIT_A) {
        A32 += (long long)z * aOffZ;
    } else {
        Ah += (long long)z * aOffZ;
        Al += (long long)z * aOffZ;
    }
    Bh += (long long)z * bOffZ;
    Bl += (long long)z * bOffZ;
    bias += (long long)z * biasOffZ;
    if constexpr (WRITE_SPLIT) {
        Ch += (long long)z * cOffZ;
        Cl += (long long)z * cOffZ;
    } else if constexpr (!FUSE) {
        C32 += (long long)z * cOffZ;
    }

    __shared__ __attribute__((aligned(16))) unsigned short sAh[4096];
    __shared__ __attribute__((aligned(16))) unsigned short sAl[4096];
    __shared__ __attribute__((aligned(16))) unsigned short sBh[4096];
    __shared__ __attribute__((aligned(16))) unsigned short sBl[4096];

    // XCD-bijective block swizzle (m204): blocks sharing an A-panel land on
    // the same XCD's L2 (FETCH 1.27 -> 0.74 GB measured).
    int nwg = gridDim.x * gridDim.y;
    int lin = blockIdx.y * gridDim.x + blockIdx.x;
    int qq = nwg >> 3, rr = nwg & 7;
    int xcd = lin & 7, idx = lin >> 3;
    int swz = (xcd < rr ? xcd * (qq + 1) : rr * (qq + 1) + (xcd - rr) * qq) + idx;
    const int tm = (swz / gridDim.x) * 128;
    const int tn = (swz % gridDim.x) * 128;

    const int tid  = threadIdx.x;
    const int lane = tid & 63;
    const int wid  = tid >> 6;
    const int wm = (wid & 1) << 6;       // wave row offset (0/64)
    const int wn = (wid >> 1) << 6;      // wave col offset (0/64)
    const int fr = lane & 15;            // fragment row/col index
    const int fk = lane >> 4;            // k-chunk 0..3
    const int swz8 = ((fk ^ ((fr + (fr >> 2)) & 3)) << 3);

    f32x4 acc[4][4];
    const f32x4 zero = {0.f, 0.f, 0.f, 0.f};
#pragma unroll
    for (int i = 0; i < 4; ++i)
#pragma unroll
        for (int j = 0; j < 4; ++j)
            acc[i][j] = zero;

    for (int k0 = 0; k0 < K; k0 += 32) {
        if constexpr (SPLIT_A) {
            stage_split_a(A32 + (long long)tm * lda + k0, lda, sAh, sAl, tid);
        } else {
            stage_lds16(Ah + (long long)tm * lda + k0, lda, sAh, tid);
            stage_lds16(Al + (long long)tm * lda + k0, lda, sAl, tid);
        }
        stage_lds16(Bh + (long long)tn * ldb + k0, ldb, sBh, tid);
        stage_lds16(Bl + (long long)tn * ldb + k0, ldb, sBl, tid);
        __syncthreads();

        s16x8 bh[4], bl[4];
#pragma unroll
        for (int ni = 0; ni < 4; ++ni) {
            int off = (wn + ni * 16 + fr) * 32 + swz8;
            bh[ni] = *(const s16x8*)(sBh + off);
            bl[ni] = *(const s16x8*)(sBl + off);
        }
#pragma unroll
        for (int mi = 0; mi < 4; ++mi) {
            int off = (wm + mi * 16 + fr) * 32 + swz8;
            s16x8 ah = *(const s16x8*)(sAh + off);
            s16x8 al = *(const s16x8*)(sAl + off);
#pragma unroll
            for (int ni = 0; ni < 4; ++ni) {
                acc[mi][ni] = __builtin_amdgcn_mfma_f32_16x16x32_bf16(ah, bh[ni], acc[mi][ni], 0, 0, 0);
                acc[mi][ni] = __builtin_amdgcn_mfma_f32_16x16x32_bf16(ah, bl[ni], acc[mi][ni], 0, 0, 0);
                acc[mi][ni] = __builtin_amdgcn_mfma_f32_16x16x32_bf16(al, bh[ni], acc[mi][ni], 0, 0, 0);
            }
        }
        __syncthreads();
    }

    // D layout: row = (lane>>4)*4 + reg (within 16-frag: fk*4+rr), col = lane&15.
    if constexpr (FUSE) {
        // fused dots: partial S_j(row) = sum over this block's 128 cols of
        // relu(acc+bias) * U[j][col];  U = {qk[0..5], vbar}.
        float Ur[4][7];
        float biasv[4];
#pragma unroll
        for (int ni = 0; ni < 4; ++ni) {
            int ccol = tn + wn + ni * 16 + fr;     // H index 0..255
            biasv[ni] = bias[ccol];
#pragma unroll
            for (int j = 0; j < 6; ++j) Ur[ni][j] = qk[j * 256 + ccol];
            Ur[ni][6] = vbar[ccol];
        }
        float qbl = 0.f;
        if (fr < 6) qbl = qb[fr];
        else if (fr == 6) qbl = vbbar[0];
        // exactly ONE of the 4 (wave, block-N) contributions per row injects
        // the constant term:
        const bool addc = ((tn + wn) == 0);
#pragma unroll
        for (int r = 0; r < 16; ++r) {
            const int mi = r >> 2, rr2 = r & 3;
            int brow = tm + wm + mi * 16 + fk * 4 + rr2;
            float p[7] = {0.f, 0.f, 0.f, 0.f, 0.f, 0.f, 0.f};
#pragma unroll
            for (int ni = 0; ni < 4; ++ni) {
                float v = acc[mi][ni][rr2] + biasv[ni];
                v = v > 0.f ? v : 0.f;
#pragma unroll
                for (int j = 0; j < 7; ++j) p[j] += v * Ur[ni][j];
            }
#pragma unroll
            for (int m = 1; m < 16; m <<= 1)
#pragma unroll
                for (int j = 0; j < 7; ++j) p[j] += __shfl_xor(p[j], m, 64);
            // lane fr emits component j = fr (constant-index select chain)
            float mine = p[0];
            mine = (fr == 1) ? p[1] : mine;
            mine = (fr == 2) ? p[2] : mine;
            mine = (fr == 3) ? p[3] : mine;
            mine = (fr == 4) ? p[4] : mine;
            mine = (fr == 5) ? p[5] : mine;
            mine = (fr == 6) ? p[6] : mine;
            if (fr < 6) {
                float val = (mine + (addc ? qbl : 0.f)) * 0.0625f;
                atomicAdd(&L[(long long)brow * 36 + fr * 6 + z], val);
            } else if (fr == 6) {
                float val = mine + (addc ? qbl : 0.f);
                atomicAdd(&Vm[(long long)brow * 6 + z], val);
            }
        }
    } else {
#pragma unroll
        for (int mi = 0; mi < 4; ++mi) {
            int crow = tm + wm + mi * 16 + fk * 4;
#pragma unroll
            for (int ni = 0; ni < 4; ++ni) {
                int ccol = tn + wn + ni * 16 + fr;
                float bv = bias[ccol];
#pragma unroll
                for (int rr2 = 0; rr2 < 4; ++rr2) {
                    float v = acc[mi][ni][rr2] + bv;
                    v = v > 0.f ? v : 0.f;
                    long long ci = (long long)(crow + rr2) * ldc + ccol;
                    if constexpr (WRITE_SPLIT) {
                        unsigned short hb = bf16rn(v);
                        Ch[ci] = hb;
                        Cl[ci] = bf16rn(v - bf16tof(hb));
                    } else {
                        C32[ci] = v;
                    }
                }
            }
        }
    }
}

// split an fp32 array into bf16 hi/lo arrays; n4 = count/4
__global__ void split_ws(const float* in, unsigned short* hi, unsigned short* lo, int n4)
{
    for (int i = blockIdx.x * 256 + threadIdx.x; i < n4; i += gridDim.x * 256) {
        float4 v = ((const float4*)in)[i];
        float xs[4] = {v.x, v.y, v.z, v.w};
        u16x4 hv, lv;
#pragma unroll
        for (int j = 0; j < 4; ++j) {
            unsigned short hb = bf16rn(xs[j]);
            hv[j] = hb;
            lv[j] = bf16rn(xs[j] - bf16tof(hb));
        }
        ((u16x4*)hi)[i] = hv;
        ((u16x4*)lo)[i] = lv;
    }
}

// zero L and Vm (contiguous region, 172032 float4s)
__global__ void zeroLV(float4* p)
{
    p[blockIdx.x * 256 + threadIdx.x] = float4{0.f, 0.f, 0.f, 0.f};
}

// grid(7) x 256: blocks 0..5 -> qk[q][:], qb[q]; block 6 -> vbar, vbbar
__global__ void precompute(const float* tq, const float* keyW, const float* keyb,
                           const float* valW, const float* valb,
                           float* qk, float* qb, float* vbar, float* vbbar)
{
    __shared__ float tqs[256];
    __shared__ float red[256];
    int h = threadIdx.x;
    int blk = blockIdx.x;
    if (blk < 6) {
        tqs[h] = tq[blk * 256 + h];
        __syncthreads();
        float acc = 0.f;
        for (int o = 0; o < 256; ++o)
            acc += tqs[o] * keyW[o * 256 + h];
        qk[blk * 256 + h] = acc;
        // qb[blk] = tq[blk] . keyb  (LDS tree reduce)
        red[h] = tqs[h] * keyb[h];
        __syncthreads();
        for (int s = 128; s > 0; s >>= 1) {
            if (h < s) red[h] += red[h + s];
            __syncthreads();
        }
        if (h == 0) qb[blk] = red[0];
    } else {
        float vb = 0.f;
        for (int o = 0; o < 256; ++o)
            vb += valW[o * 256 + h];
        vbar[h] = vb * (1.0f / 256.0f);
        red[h] = valb[h];
        __syncthreads();
        for (int s = 128; s > 0; s >>= 1) {
            if (h < s) red[h] += red[h + s];
            __syncthreads();
        }
        if (h == 0) vbbar[0] = red[0] * (1.0f / 256.0f);
    }
}

// thread per b: 6x6 softmax + sigmoid + clip
__global__ void attn(const float* L, const float* Vm, const float* biasp, float* out)
{
    int b = blockIdx.x * 256 + threadIdx.x;    // 16384, 64 blocks exact
    float bias = biasp[0];
    float l[36], vm[6];
    const float* Lr = L + (long long)b * 36;
    for (int i = 0; i < 36; ++i) l[i] = Lr[i];
    for (int k = 0; k < 6; ++k) vm[k] = Vm[(long long)b * 6 + k];
    for (int q = 0; q < 6; ++q) {
        float m = l[q * 6];
        for (int k = 1; k < 6; ++k) m = fmaxf(m, l[q * 6 + k]);
        m += 1e-8f;
        float arg[6];
        float mx = -3.402823e38f;
        for (int k = 0; k < 6; ++k) {
            arg[k] = (k == q ? 1.0f : 0.0f) + 0.1f * l[q * 6 + k] / m;
            mx = fmaxf(mx, arg[k]);
        }
        float s = 0.f, y = 0.f;
        for (int k = 0; k < 6; ++k) {
            float e = expf(arg[k] - mx);
            s += e;
            y += e * vm[k];
        }
        y /= s;
        float p = 1.0f / (1.0f + expf(-(y - bias)));
        p = fminf(fmaxf(p, 1e-7f), 1.0f - 1e-7f);
        out[(long long)b * 6 + q] = p;
    }
}

extern "C" void kernel_launch(void* const* d_in, const int* in_sizes, int n_in,
                              void* d_out, int out_size, void* d_ws, size_t ws_size,
                              hipStream_t stream)
{
    const float* x      = (const float*)d_in[0];
    const float* headW1 = (const float*)d_in[1];
    const float* headb1 = (const float*)d_in[2];
    const float* headW2 = (const float*)d_in[3];
    const float* headb2 = (const float*)d_in[4];
    const float* tq     = (const float*)d_in[5];
    const float* keyW   = (const float*)d_in[6];
    const float* keyb   = (const float*)d_in[7];
    const float* valW   = (const float*)d_in[8];
    const float* valb   = (const float*)d_in[9];
    const float* biasp  = (const float*)d_in[10];
    float* out = (float*)d_out;

    char* w = (char*)d_ws;
    float* qk    = (float*)(w + 0);
    float* vbar  = (float*)(w + 6144);
    float* qb    = (float*)(w + 7168);
    float* vbbar = (float*)(w + 7200);
    unsigned short* h1h = (unsigned short*)(w + 8192);
    unsigned short* h1l = (unsigned short*)(w + 50339840LL);
    float* L  = (float*)(w + 201334784LL);
    float* Vm = (float*)(w + 203694080LL);
    unsigned short* w1h = (unsigned short*)(w + 204087296LL);
    unsigned short* w1l = (unsigned short*)(w + 216670208LL);
    unsigned short* w2h = (unsigned short*)(w + 229253120LL);
    unsigned short* w2l = (unsigned short*)(w + 230039552LL);

    // split weights into bf16 hi/lo
    split_ws<<<1024, 256, 0, stream>>>(headW1, w1h, w1l, 1572864);
    split_ws<<<384,  256, 0, stream>>>(headW2, w2h, w2l, 98304);

    precompute<<<7, 256, 0, stream>>>(tq, keyW, keyb, valW, valb, qk, qb, vbar, vbbar);

    // zero L+Vm (contiguous 2752512 B = 172032 float4)
    zeroLV<<<672, 256, 0, stream>>>((float4*)L);

    // stage1: M=16384 N=1536 K=4096; A=x fp32 (fused split), B=w1 pre-split,
    // C -> h1 bf16 hi/lo [16384][1536]
    gemm_bf16x3<true, true, false><<<dim3(12, 128, 1), 256, 0, stream>>>(
        x, nullptr, nullptr, w1h, w1l, headb1, nullptr, h1h, h1l,
        nullptr, nullptr, nullptr, nullptr, nullptr, nullptr,
        4096, 4096, 4096, 1536, 0, 0, 0, 0);

    // stage2 (per task z): M=16384 N=256 K=256; A=h1 pre-split (lda=1536,
    // +z*256), B=w2[z], bias=headb2[z]; FUSED dots -> atomicAdd into L/Vm
    gemm_bf16x3<false, false, true><<<dim3(2, 128, 6), 256, 0, stream>>>(
        nullptr, h1h, h1l, w2h, w2l, headb2, nullptr, nullptr, nullptr,
        qk, qb, vbar, vbbar, L, Vm,
        256, 1536, 256, 0, 256, 65536, 0, 256);

    attn<<<64, 256, 0, stream>>>(L, Vm, biasp, out);
}